// Round 6
// baseline (397.575 us; speedup 1.0000x reference)
//
#include <hip/hip_runtime.h>
#include <math.h>

#define SEQ 2048
#define EMB 2048

typedef _Float16 f16;
typedef unsigned short ushort_t;
typedef __attribute__((ext_vector_type(2))) _Float16 f16x2;
typedef __attribute__((ext_vector_type(4))) _Float16 f16x4;
typedef __attribute__((ext_vector_type(8))) _Float16 f16x8;
typedef __attribute__((ext_vector_type(4))) float f32x4;
typedef __attribute__((ext_vector_type(8))) short bf16x8;
typedef __attribute__((ext_vector_type(4))) unsigned short us4;
typedef __attribute__((ext_vector_type(8))) unsigned short us8;

// async global->LDS, 16B per lane; LDS dest is lane-contiguous from lane0's ptr
__device__ __forceinline__ void gload16(const void* g, void* l) {
  __builtin_amdgcn_global_load_lds((const __attribute__((address_space(1))) unsigned int*)g,
                                   (__attribute__((address_space(3))) unsigned int*)l, 16, 0, 0);
}

__device__ __forceinline__ ushort_t f32_to_bf16(float f) {
  unsigned int u = __builtin_bit_cast(unsigned int, f);
  u += 0x7FFFu + ((u >> 16) & 1u);
  return (ushort_t)(u >> 16);
}

__device__ __forceinline__ unsigned pack2_bf16(float a, float b) {
  unsigned ua = __builtin_bit_cast(unsigned, a) + 0x8000u;
  unsigned ub = __builtin_bit_cast(unsigned, b) + 0x8000u;
  return __builtin_amdgcn_perm(ub, ua, 0x07060302u);
}
__device__ __forceinline__ us4 pack4_bf16(float a, float b, float c, float d) {
  unsigned lo = pack2_bf16(a, b);
  unsigned hi = pack2_bf16(c, d);
  unsigned long long v = ((unsigned long long)hi << 32) | (unsigned long long)lo;
  return __builtin_bit_cast(us4, v);
}

// ---------------- fp32 -> fp16 conversion, 5 tensors in one launch ----------------
__global__ __launch_bounds__(256) void cvt5_kernel(const float* __restrict__ i0,
                                                   const float* __restrict__ i1,
                                                   const float* __restrict__ i2,
                                                   const float* __restrict__ i3,
                                                   const float* __restrict__ i4,
                                                   f16* __restrict__ o0, f16* __restrict__ o1,
                                                   f16* __restrict__ o2, f16* __restrict__ o3,
                                                   f16* __restrict__ o4) {
  int b = blockIdx.x;
  int z = b >> 12;
  const float* in = (z == 0) ? i0 : (z == 1) ? i1 : (z == 2) ? i2 : (z == 3) ? i3 : i4;
  f16* out = (z == 0) ? o0 : (z == 1) ? o1 : (z == 2) ? o2 : (z == 3) ? o3 : o4;
  int i = ((b & 4095) * 256 + threadIdx.x) * 4;
  f32x4 v = *(const f32x4*)(in + i);
  *(f16x4*)(out + i) = __builtin_convertvector(v, f16x4);
}

// ---------------- RoPE tables (double precision, matches numpy) ----------------
__global__ __launch_bounds__(256) void rope_table_kernel(float* __restrict__ cosT,
                                                         float* __restrict__ sinT) {
  int id = blockIdx.x * 256 + threadIdx.x;
  int t = id >> 5, i = id & 31;
  double inv = pow(10000.0, -(double)i / 32.0);
  double ang = (double)t * inv;
  cosT[id] = (float)cos(ang);
  sinT[id] = (float)sin(ang);
}

// ---------------- RoPE apply on q (fused scale) and k, one launch ----------------
__global__ __launch_bounds__(256) void rope2_kernel(f16* __restrict__ q, f16* __restrict__ k,
                                                    const float* __restrict__ cosT,
                                                    const float* __restrict__ sinT) {
  f16* x = blockIdx.y ? k : q;
  const float scale = blockIdx.y ? 1.0f : 16.3222307f;  // sqrt(128)*log2(e) folded into q
  int id = blockIdx.x * 256 + threadIdx.x;
  int i = id & 31;
  int nh2 = (id >> 5) & 31;
  int t = id >> 10;
  float c = cosT[(t << 5) + i], s = sinT[(t << 5) + i];
  int base = t * EMB + nh2 * 64 + 2 * i;
  f16x2 p = *(f16x2*)(x + base);
  float xr = (float)p.x, xi = (float)p.y;
  f16x2 o;
  o.x = (f16)((xr * c - xi * s) * scale);
  o.y = (f16)((xr * s + xi * c) * scale);
  *(f16x2*)(x + base) = o;
}

// ---------------- Fused projection GEMM, BK=32, swizzled LDS ----------------
// z=0->q f16, z=1->k f16, z=2->v bf16 fragment-tiled vbT.
// vbT ushort index for V[t][h*128+d]:
//  ((h*32+(t>>6))*16 + ((t>>5)&1)*8 + (d>>4))*512 + (((t>>3)&3)*16 + (d&15))*8 + (t&7)
__global__ __launch_bounds__(256, 3) void proj_gemm_kernel(
    const f16* __restrict__ A, const f16* __restrict__ B0, const f16* __restrict__ B1,
    const f16* __restrict__ B2, f16* __restrict__ qout, f16* __restrict__ kout,
    ushort_t* __restrict__ vtout) {
  const int z = blockIdx.z;
  const f16* __restrict__ B = (z == 0) ? B0 : ((z == 1) ? B1 : B2);
  __shared__ f16 As[128 * 32];
  __shared__ f16 Bs[128 * 32];
  const int tid = threadIdx.x;
  const int wave = tid >> 6, lane = tid & 63;
  const int l16 = lane & 15, quad = lane >> 4;
  const int wm = (wave >> 1) << 6, wn = (wave & 1) << 6;
  const int bm = blockIdx.y << 7, bn = blockIdx.x << 7;

  // staging: lane -> row (lane>>2) of 16-row window, swizzled global chunk
  const int swg = ((lane & 3) ^ ((lane >> 3) & 3)) * 8;
  const f16* Ag = A + (size_t)(bm + wave * 32 + (lane >> 2)) * EMB + swg;
  const f16* Bg = B + (size_t)(bn + wave * 32 + (lane >> 2)) * EMB + swg;
  f16* Asl = &As[wave * 1024 + lane * 8];
  f16* Bsl = &Bs[wave * 1024 + lane * 8];

  // swizzled read offsets (precomputed, loop-invariant)
  const int swr = (quad ^ ((l16 >> 1) & 3)) * 8;
  int aoff[4], boff[4];
#pragma unroll
  for (int i = 0; i < 4; i++) {
    aoff[i] = (wm + i * 16 + l16) * 32 + swr;
    boff[i] = (wn + i * 16 + l16) * 32 + swr;
  }

  f32x4 acc[4][4];
#pragma unroll
  for (int i = 0; i < 4; i++)
#pragma unroll
    for (int j = 0; j < 4; j++) acc[i][j] = (f32x4){0.f, 0.f, 0.f, 0.f};

  for (int k0 = 0; k0 < EMB; k0 += 32) {
    __syncthreads();
    gload16(Ag + k0, Asl);
    gload16(Ag + (size_t)16 * EMB + k0, Asl + 512);
    gload16(Bg + k0, Bsl);
    gload16(Bg + (size_t)16 * EMB + k0, Bsl + 512);
    __syncthreads();
    f16x8 af[4], bf[4];
#pragma unroll
    for (int mi = 0; mi < 4; mi++) af[mi] = *(const f16x8*)&As[aoff[mi]];
#pragma unroll
    for (int ni = 0; ni < 4; ni++) bf[ni] = *(const f16x8*)&Bs[boff[ni]];
#pragma unroll
    for (int mi = 0; mi < 4; mi++)
#pragma unroll
      for (int ni = 0; ni < 4; ni++)
        acc[mi][ni] = __builtin_amdgcn_mfma_f32_16x16x32_f16(af[mi], bf[ni], acc[mi][ni], 0, 0, 0);
  }

#pragma unroll
  for (int mi = 0; mi < 4; mi++) {
#pragma unroll
    for (int ni = 0; ni < 4; ni++) {
      int row0 = bm + wm + mi * 16 + quad * 4;  // C/D: col=l16, row=quad*4+reg
      int col = bn + wn + ni * 16 + l16;
      if (z == 2) {
        us4 o;
#pragma unroll
        for (int rg = 0; rg < 4; rg++) o[rg] = f32_to_bf16(acc[mi][ni][rg]);
        int hidx = col >> 7, d = col & 127, t = row0;
        size_t idx = ((size_t)((hidx * 32 + (t >> 6)) * 16 + ((t >> 5) & 1) * 8 + (d >> 4))) * 512 +
                     (((t >> 3) & 3) * 16 + (d & 15)) * 8 + (t & 7);
        *(us4*)&vtout[idx] = o;
      } else {
        f16* Co = (z == 0) ? qout : kout;
#pragma unroll
        for (int rg = 0; rg < 4; rg++)
          Co[(size_t)(row0 + rg) * EMB + col] = (f16)acc[mi][ni][rg];
      }
    }
  }
}

// ---------------- Output GEMM: C = attn * wout^T, f32 out, 128x64 tiles, BK=32 ----------
__global__ __launch_bounds__(256, 2) void out_gemm_kernel(const f16* __restrict__ A,
                                                          const f16* __restrict__ B,
                                                          float* __restrict__ C) {
  __shared__ f16 As[128 * 32];
  __shared__ f16 Bs[64 * 32];
  const int tid = threadIdx.x;
  const int wave = tid >> 6, lane = tid & 63;
  const int l16 = lane & 15, quad = lane >> 4;
  const int wm = (wave >> 1) << 6, wn = (wave & 1) << 5;
  const int bm = blockIdx.y << 7, bn = blockIdx.x << 6;

  const int swg = ((lane & 3) ^ ((lane >> 3) & 3)) * 8;
  const f16* Ag = A + (size_t)(bm + wave * 32 + (lane >> 2)) * EMB + swg;
  const f16* Bg = B + (size_t)(bn + wave * 16 + (lane >> 2)) * EMB + swg;
  f16* Asl = &As[wave * 1024 + lane * 8];
  f16* Bsl = &Bs[wave * 512 + lane * 8];

  const int swr = (quad ^ ((l16 >> 1) & 3)) * 8;
  int aoff[4], boff[2];
#pragma unroll
  for (int i = 0; i < 4; i++) aoff[i] = (wm + i * 16 + l16) * 32 + swr;
#pragma unroll
  for (int i = 0; i < 2; i++) boff[i] = (wn + i * 16 + l16) * 32 + swr;

  f32x4 acc[4][2];
#pragma unroll
  for (int i = 0; i < 4; i++)
#pragma unroll
    for (int j = 0; j < 2; j++) acc[i][j] = (f32x4){0.f, 0.f, 0.f, 0.f};

  for (int k0 = 0; k0 < EMB; k0 += 32) {
    __syncthreads();
    gload16(Ag + k0, Asl);
    gload16(Ag + (size_t)16 * EMB + k0, Asl + 512);
    gload16(Bg + k0, Bsl);
    __syncthreads();
    f16x8 af[4], bf[2];
#pragma unroll
    for (int mi = 0; mi < 4; mi++) af[mi] = *(const f16x8*)&As[aoff[mi]];
#pragma unroll
    for (int ni = 0; ni < 2; ni++) bf[ni] = *(const f16x8*)&Bs[boff[ni]];
#pragma unroll
    for (int mi = 0; mi < 4; mi++)
#pragma unroll
      for (int ni = 0; ni < 2; ni++)
        acc[mi][ni] = __builtin_amdgcn_mfma_f32_16x16x32_f16(af[mi], bf[ni], acc[mi][ni], 0, 0, 0);
  }

#pragma unroll
  for (int mi = 0; mi < 4; mi++) {
#pragma unroll
    for (int ni = 0; ni < 2; ni++) {
      int row0 = bm + wm + mi * 16 + quad * 4;
      int col = bn + wn + ni * 16 + l16;
#pragma unroll
      for (int rg = 0; rg < 4; rg++)
        C[(size_t)(row0 + rg) * EMB + col] = acc[mi][ni][rg];
    }
  }
}

// ---------------- Differential attention v3 ----------------
// Grid (h 16, qblk 32) = 512 blocks, 3/CU (48 KB LDS). Wave = (hh = wave>>1, qs = wave&1),
// nt=2 (32 q rows). K: LDS dbuf, swizzled tiles. V: direct global A-frags from tiled vbT (L2).
// Ps[wave][nt*2+kk]: bf16 P tiles. Epilogue: hh1 waves push l-scaled O through LDS to hh0.
__global__ __launch_bounds__(256, 3) void diff_attn_v3(
    const f16* __restrict__ qb, const f16* __restrict__ kb, const ushort_t* __restrict__ vbT,
    const float* __restrict__ lq1, const float* __restrict__ lq2,
    const float* __restrict__ lk1, const float* __restrict__ lk2,
    const float* __restrict__ subw, f16* __restrict__ attnb) {
  const int h = blockIdx.x;     // head fastest -> per-XCD L2 locality for vbT/kb
  const int qblk = blockIdx.y;
  const int tid = threadIdx.x;
  const int wave = tid >> 6, lane = tid & 63;
  const int l16 = lane & 15, quad = lane >> 4;
  const int hh = wave >> 1, qs = wave & 1;

  __shared__ f16 Ks[2][8192];            // 2 x 16 KB, fragment-tiled + swizzled
  __shared__ ushort_t Ps[4][4][512];     // 16 KB

  // ---- Q B-frags (q pre-scaled by sqrt(128)*log2e at rope) ----
  const int qrow0 = qblk * 64 + qs * 32;
  f16x8 qf[2][2];  // [nt][kt]
#pragma unroll
  for (int nt = 0; nt < 2; nt++)
#pragma unroll
    for (int kt = 0; kt < 2; kt++)
      qf[nt][kt] = *(const f16x8*)(qb + (size_t)(qrow0 + nt * 16 + l16) * EMB + h * 128 +
                                   hh * 64 + kt * 32 + quad * 8);

  f32x4 O[8][2];  // [dim-tile][nt]
#pragma unroll
  for (int mt = 0; mt < 8; mt++)
#pragma unroll
    for (int nt = 0; nt < 2; nt++) O[mt][nt] = (f32x4){0.f, 0.f, 0.f, 0.f};
  float lsum[2] = {0.f, 0.f};

  // ---- K staging: wave stages keys [wave*16, wave*16+16), all 128 dims ----
  const f16* kgp = kb + (size_t)(wave * 16 + (lane >> 2)) * EMB + h * 128 + (lane & 3) * 32;
  int koff[4];
#pragma unroll
  for (int j = 0; j < 4; j++) {
    int d8 = (lane & 3) * 4 + j;
    int T = (d8 >> 3) * 8 + ((d8 >> 2) & 1) * 4 + wave;
    int ch = (d8 & 3) * 16 + (lane >> 2);
    koff[j] = T * 512 + ((ch ^ (T & 7)) * 8);
  }
  // S-phase read offsets (swizzled, loop-invariant)
  int kro[2][4];
#pragma unroll
  for (int kt = 0; kt < 2; kt++)
#pragma unroll
    for (int mt = 0; mt < 4; mt++) {
      int T = hh * 8 + kt * 4 + mt;
      kro[kt][mt] = T * 512 + ((lane ^ (T & 7)) * 8);
    }

  // ---- V: fragment-tiled global base (ushort units) ----
  const ushort_t* vg = vbT + ((size_t)h << 18) + lane * 8;

  // ---- initial tile 0 ----
  {
    f16x8 kreg[4];
#pragma unroll
    for (int j = 0; j < 4; j++) kreg[j] = *(const f16x8*)(kgp + j * 8);
#pragma unroll
    for (int j = 0; j < 4; j++) *(f16x8*)&Ks[0][koff[j]] = kreg[j];
    __syncthreads();
  }

  auto step = [&](const f16* KsC, f16* KsN, int it) {
    const size_t vit = (size_t)(it * 16) * 512;
    // V frags kk=0 (consumed after S-phase; L2 latency hidden by S)
    us8 va0[8];
#pragma unroll
    for (int mt = 0; mt < 8; mt++) va0[mt] = *(const us8*)(vg + vit + mt * 512);
    // K prefetch for next iter
    const int nxt = (it + 1 < 32) ? (it + 1) * 64 : 0;
    f16x8 kreg[4];
#pragma unroll
    for (int j = 0; j < 4; j++) kreg[j] = *(const f16x8*)(kgp + (size_t)nxt * EMB + j * 8);

    // ---- S^T = K·Q^T, exp2, P -> LDS (bf16) ----
#pragma unroll
    for (int mt = 0; mt < 4; mt++) {
      f16x8 ka0 = *(const f16x8*)&KsC[kro[0][mt]];
      f16x8 ka1 = *(const f16x8*)&KsC[kro[1][mt]];
#pragma unroll
      for (int nt = 0; nt < 2; nt++) {
        f32x4 c = (f32x4){0.f, 0.f, 0.f, 0.f};
        c = __builtin_amdgcn_mfma_f32_16x16x32_f16(ka0, qf[nt][0], c, 0, 0, 0);
        c = __builtin_amdgcn_mfma_f32_16x16x32_f16(ka1, qf[nt][1], c, 0, 0, 0);
        float p0 = __builtin_exp2f(c[0] - 28.8539008f);
        float p1 = __builtin_exp2f(c[1] - 28.8539008f);
        float p2 = __builtin_exp2f(c[2] - 28.8539008f);
        float p3 = __builtin_exp2f(c[3] - 28.8539008f);
        lsum[nt] += (p0 + p1) + (p2 + p3);
        us4 pb = pack4_bf16(p0, p1, p2, p3);
        int poff = (((mt & 1) * 2 + (quad >> 1)) * 16 + l16) * 8 + (quad & 1) * 4;
        *(us4*)&Ps[wave][nt * 2 + (mt >> 1)][poff] = pb;
      }
    }
    // V frags kk=1 (hidden behind PV kk=0)
    us8 va1[8];
#pragma unroll
    for (int mt = 0; mt < 8; mt++) va1[mt] = *(const us8*)(vg + vit + (8 + mt) * 512);

    // ---- O^T += Vt · P ---- (same-wave Ps write->read, no barrier)
    {
      bf16x8 pf0 = *(const bf16x8*)&Ps[wave][0][lane * 8];
      bf16x8 pf1 = *(const bf16x8*)&Ps[wave][2][lane * 8];
#pragma unroll
      for (int mt = 0; mt < 8; mt++) {
        bf16x8 va = __builtin_bit_cast(bf16x8, va0[mt]);
        O[mt][0] = __builtin_amdgcn_mfma_f32_16x16x32_bf16(va, pf0, O[mt][0], 0, 0, 0);
        O[mt][1] = __builtin_amdgcn_mfma_f32_16x16x32_bf16(va, pf1, O[mt][1], 0, 0, 0);
      }
    }
    {
      bf16x8 pf0 = *(const bf16x8*)&Ps[wave][1][lane * 8];
      bf16x8 pf1 = *(const bf16x8*)&Ps[wave][3][lane * 8];
#pragma unroll
      for (int mt = 0; mt < 8; mt++) {
        bf16x8 va = __builtin_bit_cast(bf16x8, va1[mt]);
        O[mt][0] = __builtin_amdgcn_mfma_f32_16x16x32_bf16(va, pf0, O[mt][0], 0, 0, 0);
        O[mt][1] = __builtin_amdgcn_mfma_f32_16x16x32_bf16(va, pf1, O[mt][1], 0, 0, 0);
      }
    }
    // stage next K tile into the other buffer
#pragma unroll
    for (int j = 0; j < 4; j++) *(f16x8*)&KsN[koff[j]] = kreg[j];
    __syncthreads();
  };

  for (int it = 0; it < 32; it += 2) {
    step(Ks[0][0] ? Ks[0] : Ks[0], Ks[1], it);  // (avoid compiler folding bufs)
    step(Ks[1], Ks[0], it + 1);
  }

  // ---- lambda + l-normalization ----
  float d1 = 0.f, d2 = 0.f;
  for (int i = 0; i < 64; i++) {
    d1 += lq1[i] * lk1[i];
    d2 += lq2[i] * lk2[i];
  }
  const float lam = __expf(d1) - __expf(d2) + 0.783605767f;
  float inv[2];
#pragma unroll
  for (int nt = 0; nt < 2; nt++) {
    float s = lsum[nt];
    s += __shfl_xor(s, 16);
    s += __shfl_xor(s, 32);
    inv[nt] = (hh == 0) ? (1.f / s) : (lam / s);
  }

  // ---- cross-half combine through LDS (reuse Ks area) ----
  float* Obuf = (float*)&Ks[0][0];  // 32 KB
  if (hh == 1) {
#pragma unroll
    for (int mt = 0; mt < 8; mt++)
#pragma unroll
      for (int nt = 0; nt < 2; nt++) {
        f32x4 v = O[mt][nt] * inv[nt];
        *(f32x4*)&Obuf[qs * 4096 + (nt * 8 + mt) * 256 + lane * 4] = v;
      }
  }
  __syncthreads();
  if (hh == 0) {
    f32x4 swv[8];
#pragma unroll
    for (int mt = 0; mt < 8; mt++) swv[mt] = *(const f32x4*)(subw + mt * 16 + quad * 4);
#pragma unroll
    for (int nt = 0; nt < 2; nt++) {
      float a[8][4];
      float ms = 0.f;
#pragma unroll
      for (int mt = 0; mt < 8; mt++) {
        f32x4 o1 = *(const f32x4*)&Obuf[qs * 4096 + (nt * 8 + mt) * 256 + lane * 4];
#pragma unroll
        for (int rg = 0; rg < 4; rg++) {
          float v = O[mt][nt][rg] * inv[nt] - o1[rg];
          a[mt][rg] = v;
          ms += v * v;
        }
      }
      ms += __shfl_xor(ms, 16);
      ms += __shfl_xor(ms, 32);
      const float rms = rsqrtf(ms * (1.f / 128.f) + 1e-5f);
      const int t_g = qrow0 + nt * 16 + l16;
#pragma unroll
      for (int mt = 0; mt < 8; mt++) {
        f16x4 o;
#pragma unroll
        for (int rg = 0; rg < 4; rg++) o[rg] = (f16)(a[mt][rg] * rms * swv[mt][rg]);
        *(f16x4*)(attnb + (size_t)t_g * EMB + h * 128 + mt * 16 + quad * 4) = o;
      }
    }
  }
}

// ---------------- launcher ----------------
extern "C" void kernel_launch(void* const* d_in, const int* in_sizes, int n_in,
                              void* d_out, int out_size, void* d_ws, size_t ws_size,
                              hipStream_t stream) {
  const float* x    = (const float*)d_in[0];
  const float* wq   = (const float*)d_in[1];
  const float* wk   = (const float*)d_in[2];
  const float* wv   = (const float*)d_in[3];
  const float* wout = (const float*)d_in[4];
  const float* lq1  = (const float*)d_in[5];
  const float* lq2  = (const float*)d_in[6];
  const float* lk1  = (const float*)d_in[7];
  const float* lk2  = (const float*)d_in[8];
  const float* subw = (const float*)d_in[9];
  float* out = (float*)d_out;

  char* ws = (char*)d_ws;
  const size_t MB = 1024 * 1024;
  f16* xb    = (f16*)(ws + 0 * MB);
  f16* wqb   = (f16*)(ws + 8 * MB);
  f16* wkb   = (f16*)(ws + 16 * MB);
  f16* wvb   = (f16*)(ws + 24 * MB);
  f16* woutb = (f16*)(ws + 32 * MB);
  f16* qb    = (f16*)(ws + 40 * MB);
  f16* kb    = (f16*)(ws + 48 * MB);
  ushort_t* vbT = (ushort_t*)(ws + 56 * MB);  // bf16, fragment-tiled per head
  f16* attnb = (f16*)(ws + 64 * MB);
  float* cosT = (float*)(ws + 72 * MB);
  float* sinT = (float*)(ws + 72 * MB + 262144);

  dim3 b256(256);
  cvt5_kernel<<<5 * 4096, b256, 0, stream>>>(x, wq, wk, wv, wout, xb, wqb, wkb, wvb, woutb);
  rope_table_kernel<<<256, b256, 0, stream>>>(cosT, sinT);

  proj_gemm_kernel<<<dim3(16, 16, 3), b256, 0, stream>>>(xb, wqb, wkb, wvb, qb, kb, vbT);

  rope2_kernel<<<dim3(8192, 2), b256, 0, stream>>>(qb, kb, cosT, sinT);

  diff_attn_v3<<<dim3(16, 32), b256, 0, stream>>>(qb, kb, vbT, lq1, lq2, lk1, lk2, subw, attnb);

  out_gemm_kernel<<<dim3(32, 16), b256, 0, stream>>>(attnb, woutb, out);
}

// Round 7
// 308.996 us; speedup vs baseline: 1.2867x; 1.2867x over previous
//
#include <hip/hip_runtime.h>
#include <math.h>

#define SEQ 2048
#define EMB 2048

typedef _Float16 f16;
typedef unsigned short ushort_t;
typedef __attribute__((ext_vector_type(2))) _Float16 f16x2;
typedef __attribute__((ext_vector_type(4))) _Float16 f16x4;
typedef __attribute__((ext_vector_type(8))) _Float16 f16x8;
typedef __attribute__((ext_vector_type(4))) float f32x4;
typedef __attribute__((ext_vector_type(8))) short bf16x8;
typedef __attribute__((ext_vector_type(4))) unsigned short us4;
typedef __attribute__((ext_vector_type(8))) unsigned short us8;

// async global->LDS, 16B per lane; LDS dest is lane-contiguous from lane0's ptr
__device__ __forceinline__ void gload16(const void* g, void* l) {
  __builtin_amdgcn_global_load_lds((const __attribute__((address_space(1))) unsigned int*)g,
                                   (__attribute__((address_space(3))) unsigned int*)l, 16, 0, 0);
}

__device__ __forceinline__ ushort_t f32_to_bf16(float f) {
  unsigned int u = __builtin_bit_cast(unsigned int, f);
  u += 0x7FFFu + ((u >> 16) & 1u);
  return (ushort_t)(u >> 16);
}

__device__ __forceinline__ unsigned pack2_bf16(float a, float b) {
  unsigned ua = __builtin_bit_cast(unsigned, a) + 0x8000u;
  unsigned ub = __builtin_bit_cast(unsigned, b) + 0x8000u;
  return __builtin_amdgcn_perm(ub, ua, 0x07060302u);
}
__device__ __forceinline__ us4 pack4_bf16(float a, float b, float c, float d) {
  unsigned lo = pack2_bf16(a, b);
  unsigned hi = pack2_bf16(c, d);
  unsigned long long v = ((unsigned long long)hi << 32) | (unsigned long long)lo;
  return __builtin_bit_cast(us4, v);
}

// ---------------- fp32 -> fp16 conversion, 5 tensors in one launch ----------------
__global__ __launch_bounds__(256) void cvt5_kernel(const float* __restrict__ i0,
                                                   const float* __restrict__ i1,
                                                   const float* __restrict__ i2,
                                                   const float* __restrict__ i3,
                                                   const float* __restrict__ i4,
                                                   f16* __restrict__ o0, f16* __restrict__ o1,
                                                   f16* __restrict__ o2, f16* __restrict__ o3,
                                                   f16* __restrict__ o4) {
  int b = blockIdx.x;
  int z = b >> 12;
  const float* in = (z == 0) ? i0 : (z == 1) ? i1 : (z == 2) ? i2 : (z == 3) ? i3 : i4;
  f16* out = (z == 0) ? o0 : (z == 1) ? o1 : (z == 2) ? o2 : (z == 3) ? o3 : o4;
  int i = ((b & 4095) * 256 + threadIdx.x) * 4;
  f32x4 v = *(const f32x4*)(in + i);
  *(f16x4*)(out + i) = __builtin_convertvector(v, f16x4);
}

// ---------------- RoPE tables (double precision, matches numpy) ----------------
__global__ __launch_bounds__(256) void rope_table_kernel(float* __restrict__ cosT,
                                                         float* __restrict__ sinT) {
  int id = blockIdx.x * 256 + threadIdx.x;
  int t = id >> 5, i = id & 31;
  double inv = pow(10000.0, -(double)i / 32.0);
  double ang = (double)t * inv;
  cosT[id] = (float)cos(ang);
  sinT[id] = (float)sin(ang);
}

// ---------------- RoPE apply on q (fused scale) and k, one launch ----------------
__global__ __launch_bounds__(256) void rope2_kernel(f16* __restrict__ q, f16* __restrict__ k,
                                                    const float* __restrict__ cosT,
                                                    const float* __restrict__ sinT) {
  f16* x = blockIdx.y ? k : q;
  const float scale = blockIdx.y ? 1.0f : 16.3222307f;  // sqrt(128)*log2(e) folded into q
  int id = blockIdx.x * 256 + threadIdx.x;
  int i = id & 31;
  int nh2 = (id >> 5) & 31;
  int t = id >> 10;
  float c = cosT[(t << 5) + i], s = sinT[(t << 5) + i];
  int base = t * EMB + nh2 * 64 + 2 * i;
  f16x2 p = *(f16x2*)(x + base);
  float xr = (float)p.x, xi = (float)p.y;
  f16x2 o;
  o.x = (f16)((xr * c - xi * s) * scale);
  o.y = (f16)((xr * s + xi * c) * scale);
  *(f16x2*)(x + base) = o;
}

// ---------------- Fused projection GEMM, BK=32, swizzled LDS ----------------
// z=0->q f16, z=1->k f16, z=2->v bf16 fragment-tiled vbT:
// vbT index for V[t][h*128+d]:
//   ((h*64 + (t>>5))*8 + (d>>4))*512 + (((t>>3)&3)*16 + (d&15))*8 + (t&7)
// i.e. per head: 64 key-blocks (32 keys) x 8 dim-tiles (16 dims); tile entry
// [lane*8+j] = V[key32 = (lane>>4)*8+j][dim16 = lane&15]  (MFMA A-frag order).
__global__ __launch_bounds__(256, 3) void proj_gemm_kernel(
    const f16* __restrict__ A, const f16* __restrict__ B0, const f16* __restrict__ B1,
    const f16* __restrict__ B2, f16* __restrict__ qout, f16* __restrict__ kout,
    ushort_t* __restrict__ vtout) {
  const int z = blockIdx.z;
  const f16* __restrict__ B = (z == 0) ? B0 : ((z == 1) ? B1 : B2);
  __shared__ f16 As[128 * 32];
  __shared__ f16 Bs[128 * 32];
  const int tid = threadIdx.x;
  const int wave = tid >> 6, lane = tid & 63;
  const int l16 = lane & 15, quad = lane >> 4;
  const int wm = (wave >> 1) << 6, wn = (wave & 1) << 6;
  const int bm = blockIdx.y << 7, bn = blockIdx.x << 7;

  const int swg = ((lane & 3) ^ ((lane >> 3) & 3)) * 8;
  const f16* Ag = A + (size_t)(bm + wave * 32 + (lane >> 2)) * EMB + swg;
  const f16* Bg = B + (size_t)(bn + wave * 32 + (lane >> 2)) * EMB + swg;
  f16* Asl = &As[wave * 1024 + lane * 8];
  f16* Bsl = &Bs[wave * 1024 + lane * 8];

  const int swr = (quad ^ ((l16 >> 1) & 3)) * 8;
  int aoff[4], boff[4];
#pragma unroll
  for (int i = 0; i < 4; i++) {
    aoff[i] = (wm + i * 16 + l16) * 32 + swr;
    boff[i] = (wn + i * 16 + l16) * 32 + swr;
  }

  f32x4 acc[4][4];
#pragma unroll
  for (int i = 0; i < 4; i++)
#pragma unroll
    for (int j = 0; j < 4; j++) acc[i][j] = (f32x4){0.f, 0.f, 0.f, 0.f};

  for (int k0 = 0; k0 < EMB; k0 += 32) {
    __syncthreads();
    gload16(Ag + k0, Asl);
    gload16(Ag + (size_t)16 * EMB + k0, Asl + 512);
    gload16(Bg + k0, Bsl);
    gload16(Bg + (size_t)16 * EMB + k0, Bsl + 512);
    __syncthreads();
    f16x8 af[4], bf[4];
#pragma unroll
    for (int mi = 0; mi < 4; mi++) af[mi] = *(const f16x8*)&As[aoff[mi]];
#pragma unroll
    for (int ni = 0; ni < 4; ni++) bf[ni] = *(const f16x8*)&Bs[boff[ni]];
#pragma unroll
    for (int mi = 0; mi < 4; mi++)
#pragma unroll
      for (int ni = 0; ni < 4; ni++)
        acc[mi][ni] = __builtin_amdgcn_mfma_f32_16x16x32_f16(af[mi], bf[ni], acc[mi][ni], 0, 0, 0);
  }

#pragma unroll
  for (int mi = 0; mi < 4; mi++) {
#pragma unroll
    for (int ni = 0; ni < 4; ni++) {
      int row0 = bm + wm + mi * 16 + quad * 4;  // C/D: col=l16, row=quad*4+reg
      int col = bn + wn + ni * 16 + l16;
      if (z == 2) {
        us4 o;
#pragma unroll
        for (int rg = 0; rg < 4; rg++) o[rg] = f32_to_bf16(acc[mi][ni][rg]);
        int hidx = col >> 7, d = col & 127, t = row0;
        size_t idx = ((size_t)((hidx * 64 + (t >> 5)) * 8 + (d >> 4))) * 512 +
                     (((t >> 3) & 3) * 16 + (d & 15)) * 8 + (t & 7);
        *(us4*)&vtout[idx] = o;
      } else {
        f16* Co = (z == 0) ? qout : kout;
#pragma unroll
        for (int rg = 0; rg < 4; rg++)
          Co[(size_t)(row0 + rg) * EMB + col] = (f16)acc[mi][ni][rg];
      }
    }
  }
}

// ---------------- Output GEMM: C = attn * wout^T, f32 out, 128x64 tiles, BK=32 ----------
__global__ __launch_bounds__(256, 2) void out_gemm_kernel(const f16* __restrict__ A,
                                                          const f16* __restrict__ B,
                                                          float* __restrict__ C) {
  __shared__ f16 As[128 * 32];
  __shared__ f16 Bs[64 * 32];
  const int tid = threadIdx.x;
  const int wave = tid >> 6, lane = tid & 63;
  const int l16 = lane & 15, quad = lane >> 4;
  const int wm = (wave >> 1) << 6, wn = (wave & 1) << 5;
  const int bm = blockIdx.y << 7, bn = blockIdx.x << 6;

  const int swg = ((lane & 3) ^ ((lane >> 3) & 3)) * 8;
  const f16* Ag = A + (size_t)(bm + wave * 32 + (lane >> 2)) * EMB + swg;
  const f16* Bg = B + (size_t)(bn + wave * 16 + (lane >> 2)) * EMB + swg;
  f16* Asl = &As[wave * 1024 + lane * 8];
  f16* Bsl = &Bs[wave * 512 + lane * 8];

  const int swr = (quad ^ ((l16 >> 1) & 3)) * 8;
  int aoff[4], boff[2];
#pragma unroll
  for (int i = 0; i < 4; i++) aoff[i] = (wm + i * 16 + l16) * 32 + swr;
#pragma unroll
  for (int i = 0; i < 2; i++) boff[i] = (wn + i * 16 + l16) * 32 + swr;

  f32x4 acc[4][2];
#pragma unroll
  for (int i = 0; i < 4; i++)
#pragma unroll
    for (int j = 0; j < 2; j++) acc[i][j] = (f32x4){0.f, 0.f, 0.f, 0.f};

  for (int k0 = 0; k0 < EMB; k0 += 32) {
    __syncthreads();
    gload16(Ag + k0, Asl);
    gload16(Ag + (size_t)16 * EMB + k0, Asl + 512);
    gload16(Bg + k0, Bsl);
    __syncthreads();
    f16x8 af[4], bf[2];
#pragma unroll
    for (int mi = 0; mi < 4; mi++) af[mi] = *(const f16x8*)&As[aoff[mi]];
#pragma unroll
    for (int ni = 0; ni < 2; ni++) bf[ni] = *(const f16x8*)&Bs[boff[ni]];
#pragma unroll
    for (int mi = 0; mi < 4; mi++)
#pragma unroll
      for (int ni = 0; ni < 2; ni++)
        acc[mi][ni] = __builtin_amdgcn_mfma_f32_16x16x32_f16(af[mi], bf[ni], acc[mi][ni], 0, 0, 0);
  }

#pragma unroll
  for (int mi = 0; mi < 4; mi++) {
#pragma unroll
    for (int ni = 0; ni < 2; ni++) {
      int row0 = bm + wm + mi * 16 + quad * 4;
      int col = bn + wn + ni * 16 + l16;
#pragma unroll
      for (int rg = 0; rg < 4; rg++)
        C[(size_t)(row0 + rg) * EMB + col] = acc[mi][ni][rg];
    }
  }
}

// ---------------- Differential attention v4 ----------------
// Grid (h 16, qblk 32) = 512 blocks, 2/CU (80 KB). Wave = (hh=wave>>1, qs=wave&1),
// 32 q rows x 1 half per wave (nt=2). K,V double-buffered in LDS with register
// prefetch; one barrier per iteration. P through per-wave LDS bounce (bf16).
// Ks tile T = hh*8 + kt*4 + mt : entry[lane*8+j] = K[mt*16+l16][hh*64+kt*32+quad*8+j]
// Vt tile T = kk*8 + dt       : entry[lane*8+j] = V[key32=quad*8+j of half kk][dim=dt*16+l16]
// Ps[wave][nt][kk][lane*8+j]  = P[key32=quad*8+j][q=nt*16+l16]
__global__ __launch_bounds__(256, 2) void diff_attn_v4(
    const f16* __restrict__ qb, const f16* __restrict__ kb, const ushort_t* __restrict__ vbT,
    const float* __restrict__ lq1, const float* __restrict__ lq2,
    const float* __restrict__ lk1, const float* __restrict__ lk2,
    const float* __restrict__ subw, f16* __restrict__ attnb) {
  const int h = blockIdx.x;     // head fastest -> 2 heads per XCD stay L2-resident
  const int qblk = blockIdx.y;
  const int tid = threadIdx.x;
  const int wave = tid >> 6, lane = tid & 63;
  const int l16 = lane & 15, quad = lane >> 4;
  const int hh = wave >> 1, qs = wave & 1;

  __shared__ f16 Ks[2][8192];           // 32 KB
  __shared__ ushort_t Vt[2][8192];      // 32 KB
  __shared__ ushort_t Ps[4][2][2][512]; // 16 KB

  // ---- Q B-frags (q pre-scaled by sqrt(128)*log2e at rope) ----
  const int qrow0 = qblk * 64 + qs * 32;
  f16x8 qf[2][2];  // [nt][kt]
#pragma unroll
  for (int nt = 0; nt < 2; nt++)
#pragma unroll
    for (int kt = 0; kt < 2; kt++)
      qf[nt][kt] = *(const f16x8*)(qb + (size_t)(qrow0 + nt * 16 + l16) * EMB + h * 128 +
                                   hh * 64 + kt * 32 + quad * 8);

  f32x4 O[8][2];  // [dim-tile][nt]
#pragma unroll
  for (int mt = 0; mt < 8; mt++)
#pragma unroll
    for (int nt = 0; nt < 2; nt++) O[mt][nt] = (f32x4){0.f, 0.f, 0.f, 0.f};
  float lsum[2] = {0.f, 0.f};

  // ---- staging addresses ----
  // K: lane reads dims (lane&3)*32 + j*8 of key wave*16+(lane>>2) (coalesced 256B rows)
  const f16* kgp = kb + (size_t)(wave * 16 + (lane >> 2)) * EMB + h * 128 + (lane & 3) * 32;
  int koff[4];
#pragma unroll
  for (int j = 0; j < 4; j++) {
    int Tk = ((lane & 3) >> 1) * 8 + ((lane & 3) & 1) * 4 + wave;
    koff[j] = Tk * 512 + (j * 16 + (lane >> 2)) * 8;
  }
  // V: fragment-tiled global; wave stages tiles T=wave*4..wave*4+3, 1KB coalesced each
  const ushort_t* vgp = vbT + ((size_t)h << 18) + (size_t)(wave * 4) * 512 + lane * 8;
  const int vo0 = (wave * 4) * 512 + lane * 8;

  // ---- initial tile 0 into buf 0 ----
  {
    f16x8 kreg[4];
    us8 vreg[4];
#pragma unroll
    for (int j = 0; j < 4; j++) kreg[j] = *(const f16x8*)(kgp + j * 8);
#pragma unroll
    for (int j = 0; j < 4; j++) vreg[j] = *(const us8*)(vgp + j * 512);
#pragma unroll
    for (int j = 0; j < 4; j++) *(f16x8*)&Ks[0][koff[j]] = kreg[j];
#pragma unroll
    for (int j = 0; j < 4; j++) *(us8*)&Vt[0][vo0 + j * 512] = vreg[j];
    __syncthreads();
  }

  auto step = [&](const f16* KsC, const ushort_t* VtC, f16* KsN, ushort_t* VtN, int it) {
    // register prefetch of tile it+1 (hidden behind the whole compute phase)
    const int nxt = (it + 1 < 32) ? (it + 1) : 0;
    f16x8 kreg[4];
    us8 vreg[4];
#pragma unroll
    for (int j = 0; j < 4; j++)
      kreg[j] = *(const f16x8*)(kgp + (size_t)(nxt * 64) * EMB + j * 8);
#pragma unroll
    for (int j = 0; j < 4; j++) vreg[j] = *(const us8*)(vgp + nxt * 8192 + j * 512);

    // ---- S^T = K·Q^T (this wave's half), exp2, P -> LDS (bf16) ----
#pragma unroll
    for (int mt = 0; mt < 4; mt++) {
      f16x8 ka0 = *(const f16x8*)&KsC[(hh * 8 + mt) * 512 + lane * 8];
      f16x8 ka1 = *(const f16x8*)&KsC[(hh * 8 + 4 + mt) * 512 + lane * 8];
#pragma unroll
      for (int nt = 0; nt < 2; nt++) {
        f32x4 c = (f32x4){0.f, 0.f, 0.f, 0.f};
        c = __builtin_amdgcn_mfma_f32_16x16x32_f16(ka0, qf[nt][0], c, 0, 0, 0);
        c = __builtin_amdgcn_mfma_f32_16x16x32_f16(ka1, qf[nt][1], c, 0, 0, 0);
        float p0 = __builtin_exp2f(c[0] - 28.8539008f);
        float p1 = __builtin_exp2f(c[1] - 28.8539008f);
        float p2 = __builtin_exp2f(c[2] - 28.8539008f);
        float p3 = __builtin_exp2f(c[3] - 28.8539008f);
        lsum[nt] += (p0 + p1) + (p2 + p3);
        us4 pb = pack4_bf16(p0, p1, p2, p3);
        int poff = (((mt & 1) * 2 + (quad >> 1)) * 16 + l16) * 8 + (quad & 1) * 4;
        *(us4*)&Ps[wave][nt][mt >> 1][poff] = pb;
      }
    }
    // same-wave Ps write->read: compiler inserts lgkmcnt, no barrier needed

    // ---- O^T += V·P ----
#pragma unroll
    for (int kk = 0; kk < 2; kk++) {
      bf16x8 pf0 = *(const bf16x8*)&Ps[wave][0][kk][lane * 8];
      bf16x8 pf1 = *(const bf16x8*)&Ps[wave][1][kk][lane * 8];
#pragma unroll
      for (int mt = 0; mt < 8; mt++) {
        bf16x8 va = *(const bf16x8*)&VtC[(kk * 8 + mt) * 512 + lane * 8];
        O[mt][0] = __builtin_amdgcn_mfma_f32_16x16x32_bf16(va, pf0, O[mt][0], 0, 0, 0);
        O[mt][1] = __builtin_amdgcn_mfma_f32_16x16x32_bf16(va, pf1, O[mt][1], 0, 0, 0);
      }
    }

    // ---- write next tile into the other buffer (nobody reads it this iter) ----
#pragma unroll
    for (int j = 0; j < 4; j++) *(f16x8*)&KsN[koff[j]] = kreg[j];
#pragma unroll
    for (int j = 0; j < 4; j++) *(us8*)&VtN[vo0 + j * 512] = vreg[j];
    __syncthreads();
  };

  for (int it = 0; it < 32; it += 2) {
    step(Ks[0], Vt[0], Ks[1], Vt[1], it);
    step(Ks[1], Vt[1], Ks[0], Vt[0], it + 1);
  }

  // ---- lambda ----
  float d1 = 0.f, d2 = 0.f;
  for (int i = 0; i < 64; i++) {
    d1 += lq1[i] * lk1[i];
    d2 += lq2[i] * lk2[i];
  }
  const float lam = __expf(d1) - __expf(d2) + 0.783605767f;

  // ---- per-q softmax denominators (reduce over quads) ----
  float inv[2];
#pragma unroll
  for (int nt = 0; nt < 2; nt++) {
    float s = lsum[nt];
    s += __shfl_xor(s, 16);
    s += __shfl_xor(s, 32);
    inv[nt] = (hh == 0) ? (1.f / s) : (lam / s);
  }

  // ---- cross-half combine through LDS (reuse Ks area, 32 KB) ----
  float* Obuf = (float*)&Ks[0][0];
  if (hh == 1) {
#pragma unroll
    for (int mt = 0; mt < 8; mt++)
#pragma unroll
      for (int nt = 0; nt < 2; nt++) {
        f32x4 v = O[mt][nt] * inv[nt];
        *(f32x4*)&Obuf[((qs * 2 + nt) * 8 + mt) * 256 + lane * 4] = v;
      }
  }
  __syncthreads();
  if (hh == 0) {
    f32x4 swv[8];
#pragma unroll
    for (int mt = 0; mt < 8; mt++) swv[mt] = *(const f32x4*)(subw + mt * 16 + quad * 4);
#pragma unroll
    for (int nt = 0; nt < 2; nt++) {
      float a[8][4];
      float ms = 0.f;
#pragma unroll
      for (int mt = 0; mt < 8; mt++) {
        f32x4 o1 = *(const f32x4*)&Obuf[((qs * 2 + nt) * 8 + mt) * 256 + lane * 4];
#pragma unroll
        for (int rg = 0; rg < 4; rg++) {
          float v = O[mt][nt][rg] * inv[nt] - o1[rg];
          a[mt][rg] = v;
          ms += v * v;
        }
      }
      ms += __shfl_xor(ms, 16);
      ms += __shfl_xor(ms, 32);
      const float rms = rsqrtf(ms * (1.f / 128.f) + 1e-5f);
      const int t_g = qrow0 + nt * 16 + l16;
#pragma unroll
      for (int mt = 0; mt < 8; mt++) {
        f16x4 o;
#pragma unroll
        for (int rg = 0; rg < 4; rg++) o[rg] = (f16)(a[mt][rg] * rms * swv[mt][rg]);
        *(f16x4*)(attnb + (size_t)t_g * EMB + h * 128 + mt * 16 + quad * 4) = o;
      }
    }
  }
}

// ---------------- launcher ----------------
extern "C" void kernel_launch(void* const* d_in, const int* in_sizes, int n_in,
                              void* d_out, int out_size, void* d_ws, size_t ws_size,
                              hipStream_t stream) {
  const float* x    = (const float*)d_in[0];
  const float* wq   = (const float*)d_in[1];
  const float* wk   = (const float*)d_in[2];
  const float* wv   = (const float*)d_in[3];
  const float* wout = (const float*)d_in[4];
  const float* lq1  = (const float*)d_in[5];
  const float* lq2  = (const float*)d_in[6];
  const float* lk1  = (const float*)d_in[7];
  const float* lk2  = (const float*)d_in[8];
  const float* subw = (const float*)d_in[9];
  float* out = (float*)d_out;

  char* ws = (char*)d_ws;
  const size_t MB = 1024 * 1024;
  f16* xb    = (f16*)(ws + 0 * MB);
  f16* wqb   = (f16*)(ws + 8 * MB);
  f16* wkb   = (f16*)(ws + 16 * MB);
  f16* wvb   = (f16*)(ws + 24 * MB);
  f16* woutb = (f16*)(ws + 32 * MB);
  f16* qb    = (f16*)(ws + 40 * MB);
  f16* kb    = (f16*)(ws + 48 * MB);
  ushort_t* vbT = (ushort_t*)(ws + 56 * MB);  // bf16, fragment-tiled per head
  f16* attnb = (f16*)(ws + 64 * MB);
  float* cosT = (float*)(ws + 72 * MB);
  float* sinT = (float*)(ws + 72 * MB + 262144);

  dim3 b256(256);
  cvt5_kernel<<<5 * 4096, b256, 0, stream>>>(x, wq, wk, wv, wout, xb, wqb, wkb, wvb, woutb);
  rope_table_kernel<<<256, b256, 0, stream>>>(cosT, sinT);

  proj_gemm_kernel<<<dim3(16, 16, 3), b256, 0, stream>>>(xb, wqb, wkb, wvb, qb, kb, vbT);

  rope2_kernel<<<dim3(8192, 2), b256, 0, stream>>>(qb, kb, cosT, sinT);

  diff_attn_v4<<<dim3(16, 32), b256, 0, stream>>>(qb, kb, vbT, lq1, lq2, lk1, lk2, subw, attnb);

  out_gemm_kernel<<<dim3(32, 16), b256, 0, stream>>>(attnb, woutb, out);
}